// Round 1
// baseline (10059.435 us; speedup 1.0000x reference)
//
#include <hip/hip_runtime.h>
#include <math.h>

#define B_  4096
#define T_  50
#define K_  32
#define D_  64
#define H_  256
#define HL_ 128
#define G4_ 512   // 4*HL

__device__ __forceinline__ float sigmoidf_(float x){ return 1.f/(1.f+expf(-x)); }

__device__ __forceinline__ float wave_reduce_sum(float v){
  #pragma unroll
  for (int off = 32; off; off >>= 1) v += __shfl_xor(v, off);
  return v;
}

// ---------------------------------------------------------------------------
// Kernel 1: per-student head. gathers, mastery, mastvec/avec, theta & a DNNs,
// attention -> bvec[B,T,D] (only t < qid_len), t_val[B], a_val[B].
// ---------------------------------------------------------------------------
__global__ __launch_bounds__(256) void head_kernel(
    const int* __restrict__ uididx, const int* __restrict__ kcodeidx,
    const int* __restrict__ kcode_len, const float* __restrict__ qidemb,
    const int* __restrict__ qid_len, const float* __restrict__ stuE,
    const float* __restrict__ knE,
    const float* __restrict__ T_W1, const float* __restrict__ T_b1,
    const float* __restrict__ T_W2, const float* __restrict__ T_b2,
    const float* __restrict__ A_W1, const float* __restrict__ A_b1,
    const float* __restrict__ A_W2, const float* __restrict__ A_b2,
    float* __restrict__ bvec, float* __restrict__ t_val, float* __restrict__ a_val)
{
  __shared__ float s_stu[D_];
  __shared__ float s_kemb[K_][D_];
  __shared__ float s_mast[K_];
  __shared__ float s_kmf[K_];
  __shared__ float s_mvec[D_];
  __shared__ float s_avec[D_];
  __shared__ float s_red[4];

  const int b    = blockIdx.x;
  const int tid  = threadIdx.x;
  const int lane = tid & 63;
  const int w    = tid >> 6;
  const int klen = kcode_len[b];
  const int qlen = qid_len[b];

  if (tid < D_) s_stu[tid] = stuE[uididx[b]*D_ + tid];
  for (int idx = tid; idx < K_*D_; idx += 256){
    int k = idx >> 6, d = idx & 63;
    s_kemb[k][d] = knE[kcodeidx[b*K_ + k]*D_ + d];
  }
  __syncthreads();

  // mastery: 8 lanes per k, bank-rotated LDS reads
  {
    int k = tid >> 3, l8 = tid & 7;
    float s = 0.f;
    #pragma unroll
    for (int j = 0; j < 8; ++j){
      int d = l8 + 8*((j + k) & 7);
      s += s_stu[d] * s_kemb[k][d];
    }
    s += __shfl_xor(s, 1); s += __shfl_xor(s, 2); s += __shfl_xor(s, 4);
    if (l8 == 0){
      float valid = (k < klen) ? 1.f : 0.f;
      s_mast[k] = valid * sigmoidf_(s * 0.2f);
      s_kmf[k]  = valid;
    }
  }
  __syncthreads();

  if (tid < D_){
    float mv = 0.f, av = 0.f;
    #pragma unroll 4
    for (int k = 0; k < K_; ++k){
      float e = s_kemb[k][tid];
      mv += s_mast[k] * e;
      av += s_kmf[k]  * e;
    }
    s_mvec[tid] = mv; s_avec[tid] = av;
  }
  __syncthreads();

  // theta DNN: thread j owns hidden column j
  {
    float acc = T_b1[tid];
    for (int d = 0; d < D_; ++d) acc += s_mvec[d] * T_W1[d*H_ + tid];
    float term = tanhf(acc) * T_W2[tid];
    term = wave_reduce_sum(term);
    if (lane == 0) s_red[w] = term;
    __syncthreads();
    if (tid == 0) t_val[b] = s_red[0] + s_red[1] + s_red[2] + s_red[3] + T_b2[0];
    __syncthreads();
  }
  // a DNN
  {
    float acc = A_b1[tid];
    for (int d = 0; d < D_; ++d) acc += s_avec[d] * A_W1[d*H_ + tid];
    float term = tanhf(acc) * A_W2[tid];
    term = wave_reduce_sum(term);
    if (lane == 0) s_red[w] = term;
    __syncthreads();
    if (tid == 0){
      float v = s_red[0] + s_red[1] + s_red[2] + s_red[3] + A_b2[0];
      a_val[b] = 8.f * (sigmoidf_(fabsf(v)) - 0.5f);
    }
  }

  // attention: one timestep per wave; all cross-lane via shuffles (no barriers)
  for (int t = w; t < qlen; t += 4){
    float qv = qidemb[(b*T_ + t)*D_ + lane];   // lane d holds q[d]
    int k  = lane >> 1;
    int hh = lane & 1;
    float sc = 0.f;
    #pragma unroll
    for (int j = 0; j < 32; ++j){
      int d = hh*32 + ((j + k) & 31);          // bank-rotated
      sc += __shfl(qv, d) * s_kemb[k][d];
    }
    sc += __shfl_xor(sc, 1);                   // full 64-elem dot, both lanes of pair
    sc = (k < klen) ? sc * 0.15f : -1e9f;
    float mx = sc;
    #pragma unroll
    for (int off = 32; off; off >>= 1) mx = fmaxf(mx, __shfl_xor(mx, off));
    float e  = expf(sc - mx);
    float sm = wave_reduce_sum(e) * 0.5f;      // each k counted twice
    float aw = e / sm;                         // identical in both lanes of the pair
    float bv = 0.f;
    #pragma unroll
    for (int k2 = 0; k2 < K_; ++k2)
      bv += __shfl(aw, 2*k2) * s_kemb[k2][lane];
    bvec[(b*T_ + t)*D_ + lane] = bv;
  }
}

// ---------------------------------------------------------------------------
// Kernel 2: LSTM. 16 students/block, 512 threads; thread owns one gate column
// with its 192 weights in VGPRs. x/h broadcast from LDS. Fused IRT epilogue.
// ---------------------------------------------------------------------------
__global__ __launch_bounds__(512) void lstm_kernel(
    const float* __restrict__ bvec, const int* __restrict__ qid_len,
    const float* __restrict__ L_Wi, const float* __restrict__ L_Wh,
    const float* __restrict__ L_b,  const float* __restrict__ L_Wo,
    const float* __restrict__ L_bo, const float* __restrict__ t_val,
    const float* __restrict__ a_val, float* __restrict__ out)
{
  __shared__ float s_x[2][16][D_];    // double-buffered inputs
  __shared__ float s_h[16][HL_];
  __shared__ float s_c[16][HL_];
  __shared__ float s_g[16][G4_];
  __shared__ int   s_len[16];

  const int tid = threadIdx.x;
  const int s0  = blockIdx.x * 16;

  // weights for this gate column, held in registers (one-time L2 read)
  float4 wx[16], wh[32];
  #pragma unroll
  for (int r = 0; r < 16; ++r){
    wx[r].x = L_Wi[(4*r+0)*G4_ + tid];
    wx[r].y = L_Wi[(4*r+1)*G4_ + tid];
    wx[r].z = L_Wi[(4*r+2)*G4_ + tid];
    wx[r].w = L_Wi[(4*r+3)*G4_ + tid];
  }
  #pragma unroll
  for (int r = 0; r < 32; ++r){
    wh[r].x = L_Wh[(4*r+0)*G4_ + tid];
    wh[r].y = L_Wh[(4*r+1)*G4_ + tid];
    wh[r].z = L_Wh[(4*r+2)*G4_ + tid];
    wh[r].w = L_Wh[(4*r+3)*G4_ + tid];
  }
  const float bias = L_b[tid];

  for (int p = tid; p < 16*HL_; p += 512){ (&s_h[0][0])[p] = 0.f; (&s_c[0][0])[p] = 0.f; }
  for (int p = tid; p < 2*16*D_; p += 512) (&s_x[0][0][0])[p] = 0.f;
  if (tid < 16) s_len[tid] = qid_len[s0 + tid];
  __syncthreads();

  // x for t=0 (qid_len >= 1 always)
  for (int p = tid; p < 16*D_; p += 512){
    int s = p >> 6, d = p & 63;
    s_x[0][s][d] = bvec[((s0+s)*T_)*D_ + d];
  }
  int maxlen = 0;
  #pragma unroll
  for (int i = 0; i < 16; ++i) maxlen = max(maxlen, s_len[i]);
  __syncthreads();

  for (int t = 0; t < maxlen; ++t){
    const int cur = t & 1, nxt = cur ^ 1;
    // prefetch next x into the other buffer
    if (t + 1 < maxlen){
      for (int p = tid; p < 16*D_; p += 512){
        int s = p >> 6, d = p & 63;
        if (t + 1 < s_len[s])
          s_x[nxt][s][d] = bvec[((s0+s)*T_ + (t+1))*D_ + d];
      }
    }
    // gates: per student, dot(192) with register weights; LDS reads are broadcasts
    #pragma unroll 1
    for (int s = 0; s < 16; ++s){
      const float4* xp = (const float4*)(&s_x[cur][s][0]);
      const float4* hp = (const float4*)(&s_h[s][0]);
      float a0 = 0.f, a1 = 0.f, a2 = 0.f, a3 = 0.f;
      #pragma unroll
      for (int r = 0; r < 16; r += 2){
        float4 xa = xp[r], xb = xp[r+1];
        a0 += wx[r].x*xa.x + wx[r].y*xa.y + wx[r].z*xa.z + wx[r].w*xa.w;
        a1 += wx[r+1].x*xb.x + wx[r+1].y*xb.y + wx[r+1].z*xb.z + wx[r+1].w*xb.w;
      }
      #pragma unroll
      for (int r = 0; r < 32; r += 4){
        float4 ha = hp[r], hb = hp[r+1], hc = hp[r+2], hd = hp[r+3];
        a0 += wh[r].x*ha.x   + wh[r].y*ha.y   + wh[r].z*ha.z   + wh[r].w*ha.w;
        a1 += wh[r+1].x*hb.x + wh[r+1].y*hb.y + wh[r+1].z*hb.z + wh[r+1].w*hb.w;
        a2 += wh[r+2].x*hc.x + wh[r+2].y*hc.y + wh[r+2].z*hc.z + wh[r+2].w*hc.w;
        a3 += wh[r+3].x*hd.x + wh[r+3].y*hd.y + wh[r+3].z*hd.z + wh[r+3].w*hd.w;
      }
      s_g[s][tid] = bias + ((a0 + a1) + (a2 + a3));
    }
    __syncthreads();
    // elementwise c/h update, masked by length
    #pragma unroll
    for (int r2 = 0; r2 < 4; ++r2){
      int p = tid + 512*r2;
      int s = p >> 7, u = p & 127;
      if (t < s_len[s]){
        float gi = s_g[s][u], gf = s_g[s][HL_+u], gg = s_g[s][2*HL_+u], go = s_g[s][3*HL_+u];
        float c  = s_c[s][u];
        float c2 = sigmoidf_(gf)*c + sigmoidf_(gi)*tanhf(gg);
        float h2 = sigmoidf_(go)*tanhf(c2);
        s_c[s][u] = c2; s_h[s][u] = h2;
      }
    }
    __syncthreads();
  }

  // epilogue: b = 8*(sigmoid(hT@L_Wo + L_bo)-0.5); out = sigmoid(a*(t-b))
  const int w    = tid >> 6;
  const int lane = tid & 63;
  for (int s = w; s < 16; s += 8){
    float part = s_h[s][lane]*L_Wo[lane] + s_h[s][lane+64]*L_Wo[64+lane];
    part = wave_reduce_sum(part);
    if (lane == 0){
      float bb = 8.f * (sigmoidf_(part + L_bo[0]) - 0.5f);
      float tv = t_val[s0+s], av = a_val[s0+s];
      out[s0+s] = sigmoidf_(av * (tv - bb));
    }
  }
}

// ---------------------------------------------------------------------------
extern "C" void kernel_launch(void* const* d_in, const int* in_sizes, int n_in,
                              void* d_out, int out_size, void* d_ws, size_t ws_size,
                              hipStream_t stream)
{
  (void)in_sizes; (void)n_in; (void)out_size; (void)ws_size;
  const int*   uididx    = (const int*)  d_in[0];
  const int*   kcodeidx  = (const int*)  d_in[1];
  const int*   kcode_len = (const int*)  d_in[2];
  const float* qidemb    = (const float*)d_in[3];
  const int*   qid_len   = (const int*)  d_in[4];
  const float* stuE      = (const float*)d_in[5];
  const float* knE       = (const float*)d_in[6];
  const float* T_W1      = (const float*)d_in[7];
  const float* T_b1      = (const float*)d_in[8];
  const float* T_W2      = (const float*)d_in[9];
  const float* T_b2      = (const float*)d_in[10];
  const float* A_W1      = (const float*)d_in[11];
  const float* A_b1      = (const float*)d_in[12];
  const float* A_W2      = (const float*)d_in[13];
  const float* A_b2      = (const float*)d_in[14];
  const float* L_Wi      = (const float*)d_in[15];
  const float* L_Wh      = (const float*)d_in[16];
  const float* L_b       = (const float*)d_in[17];
  const float* L_Wo      = (const float*)d_in[18];
  const float* L_bo      = (const float*)d_in[19];
  float* out = (float*)d_out;

  float* bvec  = (float*)d_ws;                 // B*T*D floats = 52.4 MB
  float* t_val = bvec + (size_t)B_*T_*D_;      // B floats
  float* a_val = t_val + B_;                   // B floats

  hipLaunchKernelGGL(head_kernel, dim3(B_), dim3(256), 0, stream,
    uididx, kcodeidx, kcode_len, qidemb, qid_len, stuE, knE,
    T_W1, T_b1, T_W2, T_b2, A_W1, A_b1, A_W2, A_b2,
    bvec, t_val, a_val);

  hipLaunchKernelGGL(lstm_kernel, dim3(B_/16), dim3(512), 0, stream,
    bvec, qid_len, L_Wi, L_Wh, L_b, L_Wo, L_bo, t_val, a_val, out);
}

// Round 2
// 1051.328 us; speedup vs baseline: 9.5683x; 9.5683x over previous
//
#include <hip/hip_runtime.h>
#include <math.h>

#define B_  4096
#define T_  50
#define K_  32
#define D_  64
#define H_  256
#define HL_ 128
#define G4_ 512   // 4*HL

__device__ __forceinline__ float sigmoidf_(float x){ return 1.f/(1.f+expf(-x)); }

__device__ __forceinline__ float wave_reduce_sum(float v){
  #pragma unroll
  for (int off = 32; off; off >>= 1) v += __shfl_xor(v, off);
  return v;
}

// ---------------------------------------------------------------------------
// Kernel 1: per-student head. gathers, mastery, mastvec/avec, theta & a DNNs,
// attention -> bvec[B,T,D] (only t < qid_len), t_val[B], a_val[B].
// ---------------------------------------------------------------------------
__global__ __launch_bounds__(256) void head_kernel(
    const int* __restrict__ uididx, const int* __restrict__ kcodeidx,
    const int* __restrict__ kcode_len, const float* __restrict__ qidemb,
    const int* __restrict__ qid_len, const float* __restrict__ stuE,
    const float* __restrict__ knE,
    const float* __restrict__ T_W1, const float* __restrict__ T_b1,
    const float* __restrict__ T_W2, const float* __restrict__ T_b2,
    const float* __restrict__ A_W1, const float* __restrict__ A_b1,
    const float* __restrict__ A_W2, const float* __restrict__ A_b2,
    float* __restrict__ bvec, float* __restrict__ t_val, float* __restrict__ a_val)
{
  __shared__ float s_stu[D_];
  __shared__ float s_kemb[K_][D_];
  __shared__ float s_mast[K_];
  __shared__ float s_kmf[K_];
  __shared__ float s_mvec[D_];
  __shared__ float s_avec[D_];
  __shared__ float s_red[4];

  const int b    = blockIdx.x;
  const int tid  = threadIdx.x;
  const int lane = tid & 63;
  const int w    = tid >> 6;
  const int klen = kcode_len[b];
  const int qlen = qid_len[b];

  if (tid < D_) s_stu[tid] = stuE[uididx[b]*D_ + tid];
  for (int idx = tid; idx < K_*D_; idx += 256){
    int k = idx >> 6, d = idx & 63;
    s_kemb[k][d] = knE[kcodeidx[b*K_ + k]*D_ + d];
  }
  __syncthreads();

  // mastery: 8 lanes per k, bank-rotated LDS reads
  {
    int k = tid >> 3, l8 = tid & 7;
    float s = 0.f;
    #pragma unroll
    for (int j = 0; j < 8; ++j){
      int d = l8 + 8*((j + k) & 7);
      s += s_stu[d] * s_kemb[k][d];
    }
    s += __shfl_xor(s, 1); s += __shfl_xor(s, 2); s += __shfl_xor(s, 4);
    if (l8 == 0){
      float valid = (k < klen) ? 1.f : 0.f;
      s_mast[k] = valid * sigmoidf_(s * 0.2f);
      s_kmf[k]  = valid;
    }
  }
  __syncthreads();

  if (tid < D_){
    float mv = 0.f, av = 0.f;
    #pragma unroll 4
    for (int k = 0; k < K_; ++k){
      float e = s_kemb[k][tid];
      mv += s_mast[k] * e;
      av += s_kmf[k]  * e;
    }
    s_mvec[tid] = mv; s_avec[tid] = av;
  }
  __syncthreads();

  // theta DNN: thread j owns hidden column j
  {
    float acc = T_b1[tid];
    for (int d = 0; d < D_; ++d) acc += s_mvec[d] * T_W1[d*H_ + tid];
    float term = tanhf(acc) * T_W2[tid];
    term = wave_reduce_sum(term);
    if (lane == 0) s_red[w] = term;
    __syncthreads();
    if (tid == 0) t_val[b] = s_red[0] + s_red[1] + s_red[2] + s_red[3] + T_b2[0];
    __syncthreads();
  }
  // a DNN
  {
    float acc = A_b1[tid];
    for (int d = 0; d < D_; ++d) acc += s_avec[d] * A_W1[d*H_ + tid];
    float term = tanhf(acc) * A_W2[tid];
    term = wave_reduce_sum(term);
    if (lane == 0) s_red[w] = term;
    __syncthreads();
    if (tid == 0){
      float v = s_red[0] + s_red[1] + s_red[2] + s_red[3] + A_b2[0];
      a_val[b] = 8.f * (sigmoidf_(fabsf(v)) - 0.5f);
    }
  }

  // attention: one timestep per wave; all cross-lane via shuffles (no barriers)
  for (int t = w; t < qlen; t += 4){
    float qv = qidemb[(b*T_ + t)*D_ + lane];   // lane d holds q[d]
    int k  = lane >> 1;
    int hh = lane & 1;
    float sc = 0.f;
    #pragma unroll
    for (int j = 0; j < 32; ++j){
      int d = hh*32 + ((j + k) & 31);          // bank-rotated
      sc += __shfl(qv, d) * s_kemb[k][d];
    }
    sc += __shfl_xor(sc, 1);                   // full 64-elem dot, both lanes of pair
    sc = (k < klen) ? sc * 0.15f : -1e9f;
    float mx = sc;
    #pragma unroll
    for (int off = 32; off; off >>= 1) mx = fmaxf(mx, __shfl_xor(mx, off));
    float e  = expf(sc - mx);
    float sm = wave_reduce_sum(e) * 0.5f;      // each k counted twice
    float aw = e / sm;                         // identical in both lanes of the pair
    float bv = 0.f;
    #pragma unroll
    for (int k2 = 0; k2 < K_; ++k2)
      bv += __shfl(aw, 2*k2) * s_kemb[k2][lane];
    bvec[(b*T_ + t)*D_ + lane] = bv;
  }
}

// ---------------------------------------------------------------------------
// Kernel 2: LSTM. 16 students/block, 512 threads; thread owns one gate column
// with its 192 weights in VGPRs.
// __launch_bounds__(512, 2): 2 waves/EU -> 256-VGPR budget so the 192 weight
// registers do NOT spill (round-1: plain (512) capped at 128 VGPR -> 17 GB of
// scratch traffic at 9.9 ms). Per-student early-skip halves gate FLOPs
// (E[len]=25.5 vs maxlen~47).
// ---------------------------------------------------------------------------
__global__ __launch_bounds__(512, 2) void lstm_kernel(
    const float* __restrict__ bvec, const int* __restrict__ qid_len,
    const float* __restrict__ L_Wi, const float* __restrict__ L_Wh,
    const float* __restrict__ L_b,  const float* __restrict__ L_Wo,
    const float* __restrict__ L_bo, const float* __restrict__ t_val,
    const float* __restrict__ a_val, float* __restrict__ out)
{
  __shared__ float s_x[2][16][D_];    // double-buffered inputs
  __shared__ float s_h[16][HL_];
  __shared__ float s_c[16][HL_];
  __shared__ float s_g[16][G4_];
  __shared__ int   s_len[16];

  const int tid = threadIdx.x;
  const int s0  = blockIdx.x * 16;

  // weights for this gate column, held in registers (one-time L2 read)
  float4 wx[16], wh[32];
  #pragma unroll
  for (int r = 0; r < 16; ++r){
    wx[r].x = L_Wi[(4*r+0)*G4_ + tid];
    wx[r].y = L_Wi[(4*r+1)*G4_ + tid];
    wx[r].z = L_Wi[(4*r+2)*G4_ + tid];
    wx[r].w = L_Wi[(4*r+3)*G4_ + tid];
  }
  #pragma unroll
  for (int r = 0; r < 32; ++r){
    wh[r].x = L_Wh[(4*r+0)*G4_ + tid];
    wh[r].y = L_Wh[(4*r+1)*G4_ + tid];
    wh[r].z = L_Wh[(4*r+2)*G4_ + tid];
    wh[r].w = L_Wh[(4*r+3)*G4_ + tid];
  }
  const float bias = L_b[tid];

  for (int p = tid; p < 16*HL_; p += 512){ (&s_h[0][0])[p] = 0.f; (&s_c[0][0])[p] = 0.f; }
  for (int p = tid; p < 2*16*D_; p += 512) (&s_x[0][0][0])[p] = 0.f;
  if (tid < 16) s_len[tid] = qid_len[s0 + tid];
  __syncthreads();

  // x for t=0 (qid_len >= 1 always)
  for (int p = tid; p < 16*D_; p += 512){
    int s = p >> 6, d = p & 63;
    s_x[0][s][d] = bvec[((s0+s)*T_)*D_ + d];
  }
  int maxlen = 0;
  #pragma unroll
  for (int i = 0; i < 16; ++i) maxlen = max(maxlen, s_len[i]);
  __syncthreads();

  for (int t = 0; t < maxlen; ++t){
    const int cur = t & 1, nxt = cur ^ 1;
    // prefetch next x into the other buffer
    if (t + 1 < maxlen){
      for (int p = tid; p < 16*D_; p += 512){
        int s = p >> 6, d = p & 63;
        if (t + 1 < s_len[s])
          s_x[nxt][s][d] = bvec[((s0+s)*T_ + (t+1))*D_ + d];
      }
    }
    // gates: per student, dot(192) with register weights; LDS reads broadcast.
    // skip finished students (wave-uniform branch): ~1.8x less gate work
    #pragma unroll 1
    for (int s = 0; s < 16; ++s){
      if (t >= s_len[s]) continue;
      const float4* xp = (const float4*)(&s_x[cur][s][0]);
      const float4* hp = (const float4*)(&s_h[s][0]);
      float a0 = 0.f, a1 = 0.f, a2 = 0.f, a3 = 0.f;
      #pragma unroll
      for (int r = 0; r < 16; r += 2){
        float4 xa = xp[r], xb = xp[r+1];
        a0 += wx[r].x*xa.x + wx[r].y*xa.y + wx[r].z*xa.z + wx[r].w*xa.w;
        a1 += wx[r+1].x*xb.x + wx[r+1].y*xb.y + wx[r+1].z*xb.z + wx[r+1].w*xb.w;
      }
      #pragma unroll
      for (int r = 0; r < 32; r += 4){
        float4 ha = hp[r], hb = hp[r+1], hc = hp[r+2], hd = hp[r+3];
        a0 += wh[r].x*ha.x   + wh[r].y*ha.y   + wh[r].z*ha.z   + wh[r].w*ha.w;
        a1 += wh[r+1].x*hb.x + wh[r+1].y*hb.y + wh[r+1].z*hb.z + wh[r+1].w*hb.w;
        a2 += wh[r+2].x*hc.x + wh[r+2].y*hc.y + wh[r+2].z*hc.z + wh[r+2].w*hc.w;
        a3 += wh[r+3].x*hd.x + wh[r+3].y*hd.y + wh[r+3].z*hd.z + wh[r+3].w*hd.w;
      }
      s_g[s][tid] = bias + ((a0 + a1) + (a2 + a3));
    }
    __syncthreads();
    // elementwise c/h update, masked by length
    #pragma unroll
    for (int r2 = 0; r2 < 4; ++r2){
      int p = tid + 512*r2;
      int s = p >> 7, u = p & 127;
      if (t < s_len[s]){
        float gi = s_g[s][u], gf = s_g[s][HL_+u], gg = s_g[s][2*HL_+u], go = s_g[s][3*HL_+u];
        float c  = s_c[s][u];
        float c2 = sigmoidf_(gf)*c + sigmoidf_(gi)*tanhf(gg);
        float h2 = sigmoidf_(go)*tanhf(c2);
        s_c[s][u] = c2; s_h[s][u] = h2;
      }
    }
    __syncthreads();
  }

  // epilogue: b = 8*(sigmoid(hT@L_Wo + L_bo)-0.5); out = sigmoid(a*(t-b))
  const int w    = tid >> 6;
  const int lane = tid & 63;
  for (int s = w; s < 16; s += 8){
    float part = s_h[s][lane]*L_Wo[lane] + s_h[s][lane+64]*L_Wo[64+lane];
    part = wave_reduce_sum(part);
    if (lane == 0){
      float bb = 8.f * (sigmoidf_(part + L_bo[0]) - 0.5f);
      float tv = t_val[s0+s], av = a_val[s0+s];
      out[s0+s] = sigmoidf_(av * (tv - bb));
    }
  }
}

// ---------------------------------------------------------------------------
extern "C" void kernel_launch(void* const* d_in, const int* in_sizes, int n_in,
                              void* d_out, int out_size, void* d_ws, size_t ws_size,
                              hipStream_t stream)
{
  (void)in_sizes; (void)n_in; (void)out_size; (void)ws_size;
  const int*   uididx    = (const int*)  d_in[0];
  const int*   kcodeidx  = (const int*)  d_in[1];
  const int*   kcode_len = (const int*)  d_in[2];
  const float* qidemb    = (const float*)d_in[3];
  const int*   qid_len   = (const int*)  d_in[4];
  const float* stuE      = (const float*)d_in[5];
  const float* knE       = (const float*)d_in[6];
  const float* T_W1      = (const float*)d_in[7];
  const float* T_b1      = (const float*)d_in[8];
  const float* T_W2      = (const float*)d_in[9];
  const float* T_b2      = (const float*)d_in[10];
  const float* A_W1      = (const float*)d_in[11];
  const float* A_b1      = (const float*)d_in[12];
  const float* A_W2      = (const float*)d_in[13];
  const float* A_b2      = (const float*)d_in[14];
  const float* L_Wi      = (const float*)d_in[15];
  const float* L_Wh      = (const float*)d_in[16];
  const float* L_b       = (const float*)d_in[17];
  const float* L_Wo      = (const float*)d_in[18];
  const float* L_bo      = (const float*)d_in[19];
  float* out = (float*)d_out;

  float* bvec  = (float*)d_ws;                 // B*T*D floats = 52.4 MB
  float* t_val = bvec + (size_t)B_*T_*D_;      // B floats
  float* a_val = t_val + B_;                   // B floats

  hipLaunchKernelGGL(head_kernel, dim3(B_), dim3(256), 0, stream,
    uididx, kcodeidx, kcode_len, qidemb, qid_len, stuE, knE,
    T_W1, T_b1, T_W2, T_b2, A_W1, A_b1, A_W2, A_b2,
    bvec, t_val, a_val);

  hipLaunchKernelGGL(lstm_kernel, dim3(B_/16), dim3(512), 0, stream,
    bvec, qid_len, L_Wi, L_Wh, L_b, L_Wo, L_bo, t_val, a_val, out);
}

// Round 3
// 380.892 us; speedup vs baseline: 26.4102x; 2.7602x over previous
//
#include <hip/hip_runtime.h>
#include <math.h>

#define B_  4096
#define T_  50
#define K_  32
#define D_  64
#define H_  256
#define HL_ 128
#define G4_ 512   // 4*HL

typedef __attribute__((ext_vector_type(8))) short bf16x8;
typedef __attribute__((ext_vector_type(4))) float f32x4;

__device__ __forceinline__ float sigmoidf_(float x){ return 1.f/(1.f+expf(-x)); }

__device__ __forceinline__ short f2bf(float f){
  union { float f; unsigned u; } v; v.f = f;
  unsigned r = v.u + 0x7FFFu + ((v.u >> 16) & 1u);   // round-to-nearest-even
  return (short)(r >> 16);
}

__device__ __forceinline__ float wave_reduce_sum(float v){
  #pragma unroll
  for (int off = 32; off; off >>= 1) v += __shfl_xor(v, off);
  return v;
}

// ---------------------------------------------------------------------------
// Kernel 1: per-student head (unchanged from R2). gathers, mastery,
// mastvec/avec, theta & a DNNs, attention -> bvec[B,T,D], t_val[B], a_val[B].
// ---------------------------------------------------------------------------
__global__ __launch_bounds__(256) void head_kernel(
    const int* __restrict__ uididx, const int* __restrict__ kcodeidx,
    const int* __restrict__ kcode_len, const float* __restrict__ qidemb,
    const int* __restrict__ qid_len, const float* __restrict__ stuE,
    const float* __restrict__ knE,
    const float* __restrict__ T_W1, const float* __restrict__ T_b1,
    const float* __restrict__ T_W2, const float* __restrict__ T_b2,
    const float* __restrict__ A_W1, const float* __restrict__ A_b1,
    const float* __restrict__ A_W2, const float* __restrict__ A_b2,
    float* __restrict__ bvec, float* __restrict__ t_val, float* __restrict__ a_val)
{
  __shared__ float s_stu[D_];
  __shared__ float s_kemb[K_][D_];
  __shared__ float s_mast[K_];
  __shared__ float s_kmf[K_];
  __shared__ float s_mvec[D_];
  __shared__ float s_avec[D_];
  __shared__ float s_red[4];

  const int b    = blockIdx.x;
  const int tid  = threadIdx.x;
  const int lane = tid & 63;
  const int w    = tid >> 6;
  const int klen = kcode_len[b];
  const int qlen = qid_len[b];

  if (tid < D_) s_stu[tid] = stuE[uididx[b]*D_ + tid];
  for (int idx = tid; idx < K_*D_; idx += 256){
    int k = idx >> 6, d = idx & 63;
    s_kemb[k][d] = knE[kcodeidx[b*K_ + k]*D_ + d];
  }
  __syncthreads();

  {
    int k = tid >> 3, l8 = tid & 7;
    float s = 0.f;
    #pragma unroll
    for (int j = 0; j < 8; ++j){
      int d = l8 + 8*((j + k) & 7);
      s += s_stu[d] * s_kemb[k][d];
    }
    s += __shfl_xor(s, 1); s += __shfl_xor(s, 2); s += __shfl_xor(s, 4);
    if (l8 == 0){
      float valid = (k < klen) ? 1.f : 0.f;
      s_mast[k] = valid * sigmoidf_(s * 0.2f);
      s_kmf[k]  = valid;
    }
  }
  __syncthreads();

  if (tid < D_){
    float mv = 0.f, av = 0.f;
    #pragma unroll 4
    for (int k = 0; k < K_; ++k){
      float e = s_kemb[k][tid];
      mv += s_mast[k] * e;
      av += s_kmf[k]  * e;
    }
    s_mvec[tid] = mv; s_avec[tid] = av;
  }
  __syncthreads();

  {
    float acc = T_b1[tid];
    for (int d = 0; d < D_; ++d) acc += s_mvec[d] * T_W1[d*H_ + tid];
    float term = tanhf(acc) * T_W2[tid];
    term = wave_reduce_sum(term);
    if (lane == 0) s_red[w] = term;
    __syncthreads();
    if (tid == 0) t_val[b] = s_red[0] + s_red[1] + s_red[2] + s_red[3] + T_b2[0];
    __syncthreads();
  }
  {
    float acc = A_b1[tid];
    for (int d = 0; d < D_; ++d) acc += s_avec[d] * A_W1[d*H_ + tid];
    float term = tanhf(acc) * A_W2[tid];
    term = wave_reduce_sum(term);
    if (lane == 0) s_red[w] = term;
    __syncthreads();
    if (tid == 0){
      float v = s_red[0] + s_red[1] + s_red[2] + s_red[3] + A_b2[0];
      a_val[b] = 8.f * (sigmoidf_(fabsf(v)) - 0.5f);
    }
  }

  for (int t = w; t < qlen; t += 4){
    float qv = qidemb[(b*T_ + t)*D_ + lane];
    int k  = lane >> 1;
    int hh = lane & 1;
    float sc = 0.f;
    #pragma unroll
    for (int j = 0; j < 32; ++j){
      int d = hh*32 + ((j + k) & 31);
      sc += __shfl(qv, d) * s_kemb[k][d];
    }
    sc += __shfl_xor(sc, 1);
    sc = (k < klen) ? sc * 0.15f : -1e9f;
    float mx = sc;
    #pragma unroll
    for (int off = 32; off; off >>= 1) mx = fmaxf(mx, __shfl_xor(mx, off));
    float e  = expf(sc - mx);
    float sm = wave_reduce_sum(e) * 0.5f;
    float aw = e / sm;
    float bv = 0.f;
    #pragma unroll
    for (int k2 = 0; k2 < K_; ++k2)
      bv += __shfl(aw, 2*k2) * s_kemb[k2][lane];
    bvec[(b*T_ + t)*D_ + lane] = bv;
  }
}

// ---------------------------------------------------------------------------
// Kernel 2: MFMA LSTM. 16 students/block (M=16), 512 threads = 8 waves.
// Per step: gates[16x512] = A[16x192] @ W[192x512] via mfma_f32_16x16x32_bf16.
// Wave w owns cols [w*64, w*64+64): 4 N-tiles x 6 K-tiles = 24 B-fragments
// (96 VGPRs of bf16 weights) loaded from HBM ONCE — as mfma operands they are
// conversion results, not rematerializable loads, so the allocator keeps them
// (R2 failure mode: plain fp32 weight arrays got re-loaded from L2 every
// s-iter -> 41 GB L2 traffic, 863 us). A = [x|h] bf16 in LDS: 6 ds_read_b128
// per wave per step. State c,h stays fp32 in LDS. Bias pre-loaded into the
// accumulator init. Fused IRT epilogue.
// ---------------------------------------------------------------------------
#define AROW 200   // bf16 row stride of s_A: 400 B = 100 dwords -> 4-bank step, 2-way max (free)

__global__ __launch_bounds__(512, 2) void lstm_kernel(
    const float* __restrict__ bvec, const int* __restrict__ qid_len,
    const float* __restrict__ L_Wi, const float* __restrict__ L_Wh,
    const float* __restrict__ L_b,  const float* __restrict__ L_Wo,
    const float* __restrict__ L_bo, const float* __restrict__ t_val,
    const float* __restrict__ a_val, float* __restrict__ out)
{
  __shared__ short s_A[16*AROW];       // [student][k=0..63:x, 64..191:h] bf16
  __shared__ float s_g[16*513];        // gates fp32, row pad +1 dword
  __shared__ float s_c[16][HL_];
  __shared__ float s_h[16][HL_];
  __shared__ int   s_len[16];

  const int tid  = threadIdx.x;
  const int s0   = blockIdx.x * 16;
  const int w    = tid >> 6;
  const int lane = tid & 63;
  const int l15  = lane & 15;
  const int quad = lane >> 4;
  const int colbase = w*64;

  // B fragments: wf[nt][kt][j] = W[kt*32 + quad*8 + j][colbase + nt*16 + l15]
  bf16x8 wf[4][6];
  #pragma unroll
  for (int nt = 0; nt < 4; ++nt){
    const int col = colbase + nt*16 + l15;
    #pragma unroll
    for (int kt = 0; kt < 6; ++kt){
      #pragma unroll
      for (int j = 0; j < 8; ++j){
        int k = kt*32 + quad*8 + j;
        float v = (k < D_) ? L_Wi[k*G4_ + col] : L_Wh[(k-D_)*G4_ + col];
        wf[nt][kt][j] = f2bf(v);
      }
    }
  }
  float biasv[4];
  #pragma unroll
  for (int nt = 0; nt < 4; ++nt) biasv[nt] = L_b[colbase + nt*16 + l15];

  for (int p = tid; p < 16*HL_; p += 512){ (&s_c[0][0])[p] = 0.f; (&s_h[0][0])[p] = 0.f; }
  for (int p = tid; p < 16*AROW; p += 512) s_A[p] = 0;
  if (tid < 16) s_len[tid] = qid_len[s0 + tid];
  __syncthreads();

  // stage x(0): 16 students x 32 float2 = 512 slots
  const int xs = tid >> 5, xpos = tid & 31;
  {
    const float2 xv = *(const float2*)&bvec[((size_t)(s0+xs)*T_ + 0)*D_ + xpos*2];
    s_A[xs*AROW + xpos*2]     = f2bf(xv.x);
    s_A[xs*AROW + xpos*2 + 1] = f2bf(xv.y);
  }
  int maxlen = 0;
  #pragma unroll
  for (int i = 0; i < 16; ++i) maxlen = max(maxlen, s_len[i]);
  __syncthreads();

  for (int t = 0; t < maxlen; ++t){
    // gates = bias + A @ W  (A-frag: A[m=l15][k=quad*8+j] per K-tile)
    f32x4 acc[4];
    #pragma unroll
    for (int nt = 0; nt < 4; ++nt){
      f32x4 a; a[0]=biasv[nt]; a[1]=biasv[nt]; a[2]=biasv[nt]; a[3]=biasv[nt];
      acc[nt] = a;
    }
    #pragma unroll
    for (int kt = 0; kt < 6; ++kt){
      bf16x8 af = *(const bf16x8*)&s_A[l15*AROW + kt*32 + quad*8];
      #pragma unroll
      for (int nt = 0; nt < 4; ++nt)
        acc[nt] = __builtin_amdgcn_mfma_f32_16x16x32_bf16(af, wf[nt][kt], acc[nt], 0, 0, 0);
    }
    // prefetch x(t+1) while MFMAs drain (finished students read harmless poison)
    float2 xv;
    const bool havex = (t + 1 < maxlen);
    if (havex) xv = *(const float2*)&bvec[((size_t)(s0+xs)*T_ + (t+1))*D_ + xpos*2];
    // C layout: row = quad*4 + r (student), col = colbase + nt*16 + l15 (gate)
    #pragma unroll
    for (int nt = 0; nt < 4; ++nt){
      const int col = colbase + nt*16 + l15;
      #pragma unroll
      for (int r = 0; r < 4; ++r)
        s_g[(quad*4 + r)*513 + col] = acc[nt][r];
    }
    __syncthreads();
    // elementwise c/h update, masked by length
    #pragma unroll
    for (int r2 = 0; r2 < 4; ++r2){
      int p = tid + 512*r2;
      int s = p >> 7, u = p & 127;
      if (t < s_len[s]){
        float gi = s_g[s*513 + u],       gf = s_g[s*513 + HL_ + u];
        float gg = s_g[s*513 + 2*HL_ + u], go = s_g[s*513 + 3*HL_ + u];
        float c  = s_c[s][u];
        float c2 = sigmoidf_(gf)*c + sigmoidf_(gi)*tanhf(gg);
        float h2 = sigmoidf_(go)*tanhf(c2);
        s_c[s][u] = c2; s_h[s][u] = h2;
        s_A[s*AROW + D_ + u] = f2bf(h2);
      }
    }
    if (havex){
      s_A[xs*AROW + xpos*2]     = f2bf(xv.x);
      s_A[xs*AROW + xpos*2 + 1] = f2bf(xv.y);
    }
    __syncthreads();
  }

  // epilogue: b = 8*(sigmoid(hT@L_Wo + L_bo)-0.5); out = sigmoid(a*(t-b))
  for (int s2 = w; s2 < 16; s2 += 8){
    float part = s_h[s2][lane]*L_Wo[lane] + s_h[s2][lane+64]*L_Wo[64+lane];
    part = wave_reduce_sum(part);
    if (lane == 0){
      float bb = 8.f * (sigmoidf_(part + L_bo[0]) - 0.5f);
      out[s0+s2] = sigmoidf_(a_val[s0+s2] * (t_val[s0+s2] - bb));
    }
  }
}

// ---------------------------------------------------------------------------
extern "C" void kernel_launch(void* const* d_in, const int* in_sizes, int n_in,
                              void* d_out, int out_size, void* d_ws, size_t ws_size,
                              hipStream_t stream)
{
  (void)in_sizes; (void)n_in; (void)out_size; (void)ws_size;
  const int*   uididx    = (const int*)  d_in[0];
  const int*   kcodeidx  = (const int*)  d_in[1];
  const int*   kcode_len = (const int*)  d_in[2];
  const float* qidemb    = (const float*)d_in[3];
  const int*   qid_len   = (const int*)  d_in[4];
  const float* stuE      = (const float*)d_in[5];
  const float* knE       = (const float*)d_in[6];
  const float* T_W1      = (const float*)d_in[7];
  const float* T_b1      = (const float*)d_in[8];
  const float* T_W2      = (const float*)d_in[9];
  const float* T_b2      = (const float*)d_in[10];
  const float* A_W1      = (const float*)d_in[11];
  const float* A_b1      = (const float*)d_in[12];
  const float* A_W2      = (const float*)d_in[13];
  const float* A_b2      = (const float*)d_in[14];
  const float* L_Wi      = (const float*)d_in[15];
  const float* L_Wh      = (const float*)d_in[16];
  const float* L_b       = (const float*)d_in[17];
  const float* L_Wo      = (const float*)d_in[18];
  const float* L_bo      = (const float*)d_in[19];
  float* out = (float*)d_out;

  float* bvec  = (float*)d_ws;                 // B*T*D floats = 52.4 MB
  float* t_val = bvec + (size_t)B_*T_*D_;      // B floats
  float* a_val = t_val + B_;                   // B floats

  hipLaunchKernelGGL(head_kernel, dim3(B_), dim3(256), 0, stream,
    uididx, kcodeidx, kcode_len, qidemb, qid_len, stuE, knE,
    T_W1, T_b1, T_W2, T_b2, A_W1, A_b1, A_W2, A_b2,
    bvec, t_val, a_val);

  hipLaunchKernelGGL(lstm_kernel, dim3(B_/16), dim3(512), 0, stream,
    bvec, qid_len, L_Wi, L_Wh, L_b, L_Wo, L_bo, t_val, a_val, out);
}

// Round 4
// 300.652 us; speedup vs baseline: 33.4587x; 1.2669x over previous
//
#include <hip/hip_runtime.h>
#include <math.h>

#define B_  4096
#define T_  50
#define K_  32
#define D_  64
#define H_  256
#define HL_ 128
#define G4_ 512   // 4*HL

typedef __attribute__((ext_vector_type(8))) short bf16x8;
typedef __attribute__((ext_vector_type(4))) float f32x4;

__device__ __forceinline__ float sigmoidf_(float x){ return 1.f/(1.f+expf(-x)); }

__device__ __forceinline__ short f2bf(float f){
  union { float f; unsigned u; } v; v.f = f;
  unsigned r = v.u + 0x7FFFu + ((v.u >> 16) & 1u);   // round-to-nearest-even
  return (short)(r >> 16);
}
__device__ __forceinline__ float bf2f(short s){
  union { unsigned u; float f; } v; v.u = ((unsigned)(unsigned short)s) << 16;
  return v.f;
}

__device__ __forceinline__ float wave_reduce_sum(float v){
  #pragma unroll
  for (int off = 32; off; off >>= 1) v += __shfl_xor(v, off);
  return v;
}

// ---------------------------------------------------------------------------
// Kernel 1: per-student head. R3 was LDS-pipe bound (shuffle attention:
// VALUBusy 26%, 7.7e6 bank conflicts). Now: attention via MFMA.
// scores[64x32] = Q @ kemb^T (2 kt x 2 nt), softmax in-register,
// P -> LDS (C-layout -> A-layout transform, within-wave), bvec = P @ kemb
// (4 nt, K=32 = one K-tile). bvec emitted as bf16 (lstm consumed bf16 anyway).
// ---------------------------------------------------------------------------
#define KROW 72   // s_kemb row stride (shorts); 72%8==0 -> 16B-aligned rows
#define QROW 72
#define PROW 40   // s_p / s_kembT row stride (shorts)

__global__ __launch_bounds__(256) void head_kernel(
    const int* __restrict__ uididx, const int* __restrict__ kcodeidx,
    const int* __restrict__ kcode_len, const float* __restrict__ qidemb,
    const int* __restrict__ qid_len, const float* __restrict__ stuE,
    const float* __restrict__ knE,
    const float* __restrict__ T_W1, const float* __restrict__ T_b1,
    const float* __restrict__ T_W2, const float* __restrict__ T_b2,
    const float* __restrict__ A_W1, const float* __restrict__ A_b1,
    const float* __restrict__ A_W2, const float* __restrict__ A_b2,
    short* __restrict__ bvec, float* __restrict__ t_val, float* __restrict__ a_val)
{
  __shared__ __align__(16) short s_kemb[K_*KROW];   // [k][d] bf16 (scores B)
  __shared__ __align__(16) short s_kembT[D_*PROW];  // [d][k] bf16 (PV B)
  __shared__ __align__(16) short s_q[64*QROW];      // [t][d] bf16 (scores A)
  __shared__ __align__(16) short s_p[64*PROW];      // [t][k] bf16 (PV A)
  __shared__ float s_stu[D_];
  __shared__ float s_mast[K_];
  __shared__ float s_kmf[K_];
  __shared__ float s_mvec[D_];
  __shared__ float s_avec[D_];
  __shared__ float s_red[4];

  const int b    = blockIdx.x;
  const int tid  = threadIdx.x;
  const int lane = tid & 63;
  const int w    = tid >> 6;
  const int l15  = lane & 15;
  const int quad = lane >> 4;
  const int klen = kcode_len[b];
  const int qlen = qid_len[b];

  if (tid < D_) s_stu[tid] = stuE[uididx[b]*D_ + tid];
  // kemb: bf16, both layouts
  for (int idx = tid; idx < K_*D_; idx += 256){
    int k = idx >> 6, d = idx & 63;
    short bv = f2bf(knE[kcodeidx[b*K_ + k]*D_ + d]);
    s_kemb[k*KROW + d]  = bv;
    s_kembT[d*PROW + k] = bv;
  }
  // q: bf16, rows >= qlen zeroed (keeps softmax of dead rows finite)
  for (int idx = tid; idx < 64*D_; idx += 256){
    int t = idx >> 6, d = idx & 63;
    s_q[t*QROW + d] = (t < qlen) ? f2bf(qidemb[(b*T_ + t)*D_ + d]) : (short)0;
  }
  __syncthreads();

  // mastery: 8 lanes per k, bank-rotated
  {
    int k = tid >> 3, l8 = tid & 7;
    float s = 0.f;
    #pragma unroll
    for (int j = 0; j < 8; ++j){
      int d = l8 + 8*((j + k) & 7);
      s += s_stu[d] * bf2f(s_kemb[k*KROW + d]);
    }
    s += __shfl_xor(s, 1); s += __shfl_xor(s, 2); s += __shfl_xor(s, 4);
    if (l8 == 0){
      float valid = (k < klen) ? 1.f : 0.f;
      s_mast[k] = valid * sigmoidf_(s * 0.2f);
      s_kmf[k]  = valid;
    }
  }
  __syncthreads();

  if (tid < D_){
    float mv = 0.f, av = 0.f;
    #pragma unroll 4
    for (int k = 0; k < K_; ++k){
      float e = bf2f(s_kemb[k*KROW + tid]);
      mv += s_mast[k] * e;
      av += s_kmf[k]  * e;
    }
    s_mvec[tid] = mv; s_avec[tid] = av;
  }
  __syncthreads();

  // ---- attention (interleaved with DNNs below; independent units) ----
  {
    // scores: C[t][k] ; A = Q[m=t][kdim=d], B[kdim=d][n=k] read from kemb[k][d]
    f32x4 zero = {0.f, 0.f, 0.f, 0.f};
    f32x4 accs[2] = {zero, zero};
    #pragma unroll
    for (int kt = 0; kt < 2; ++kt){
      bf16x8 aq = *(const bf16x8*)&s_q[(w*16 + l15)*QROW + kt*32 + quad*8];
      #pragma unroll
      for (int nt = 0; nt < 2; ++nt){
        bf16x8 bk = *(const bf16x8*)&s_kemb[(nt*16 + l15)*KROW + kt*32 + quad*8];
        accs[nt] = __builtin_amdgcn_mfma_f32_16x16x32_bf16(aq, bk, accs[nt], 0, 0, 0);
      }
    }
    // softmax over 32 cols; row t = w*16 + quad*4 + r, cols nt*16 + l15
    #pragma unroll
    for (int r = 0; r < 4; ++r){
      float v0 = (l15      < klen) ? accs[0][r]*0.15f : -1e9f;
      float v1 = (l15 + 16 < klen) ? accs[1][r]*0.15f : -1e9f;
      float mx = fmaxf(v0, v1);
      #pragma unroll
      for (int off = 1; off < 16; off <<= 1) mx = fmaxf(mx, __shfl_xor(mx, off));
      float e0 = expf(v0 - mx), e1 = expf(v1 - mx);
      float sm = e0 + e1;
      #pragma unroll
      for (int off = 1; off < 16; off <<= 1) sm += __shfl_xor(sm, off);
      float inv = 1.f / sm;
      int row = w*16 + quad*4 + r;
      s_p[row*PROW + l15]      = f2bf(e0 * inv);
      s_p[row*PROW + 16 + l15] = f2bf(e1 * inv);
    }
    // PV: within-wave LDS round trip (wave w owns rows [w*16, w*16+16))
    bf16x8 ap = *(const bf16x8*)&s_p[(w*16 + l15)*PROW + quad*8];
    #pragma unroll
    for (int nt = 0; nt < 4; ++nt){
      bf16x8 bv = *(const bf16x8*)&s_kembT[(nt*16 + l15)*PROW + quad*8];
      f32x4 acco = __builtin_amdgcn_mfma_f32_16x16x32_bf16(ap, bv, zero, 0, 0, 0);
      #pragma unroll
      for (int r = 0; r < 4; ++r){
        int t = w*16 + quad*4 + r;
        if (t < qlen) bvec[((size_t)b*T_ + t)*D_ + nt*16 + l15] = f2bf(acco[r]);
      }
    }
  }

  // theta DNN: thread j owns hidden column j
  {
    float acc = T_b1[tid];
    for (int d = 0; d < D_; ++d) acc += s_mvec[d] * T_W1[d*H_ + tid];
    float term = tanhf(acc) * T_W2[tid];
    term = wave_reduce_sum(term);
    if (lane == 0) s_red[w] = term;
    __syncthreads();
    if (tid == 0) t_val[b] = s_red[0] + s_red[1] + s_red[2] + s_red[3] + T_b2[0];
    __syncthreads();
  }
  // a DNN
  {
    float acc = A_b1[tid];
    for (int d = 0; d < D_; ++d) acc += s_avec[d] * A_W1[d*H_ + tid];
    float term = tanhf(acc) * A_W2[tid];
    term = wave_reduce_sum(term);
    if (lane == 0) s_red[w] = term;
    __syncthreads();
    if (tid == 0){
      float v = s_red[0] + s_red[1] + s_red[2] + s_red[3] + A_b2[0];
      a_val[b] = 8.f * (sigmoidf_(fabsf(v)) - 0.5f);
    }
  }
}

// ---------------------------------------------------------------------------
// Kernel 2: MFMA LSTM (unchanged logic from R3; bvec input now bf16).
// 16 students/block, 512 threads = 8 waves; wave owns 64 gate cols, weights
// as 24 bf16x8 B-fragments in VGPRs (loaded once). State c,h fp32 in LDS.
// ---------------------------------------------------------------------------
#define AROW 200   // bf16 row stride of s_A

__global__ __launch_bounds__(512, 2) void lstm_kernel(
    const short* __restrict__ bvec, const int* __restrict__ qid_len,
    const float* __restrict__ L_Wi, const float* __restrict__ L_Wh,
    const float* __restrict__ L_b,  const float* __restrict__ L_Wo,
    const float* __restrict__ L_bo, const float* __restrict__ t_val,
    const float* __restrict__ a_val, float* __restrict__ out)
{
  __shared__ __align__(16) short s_A[16*AROW];  // [student][k=0..63:x, 64..191:h] bf16
  __shared__ float s_g[16*513];                 // gates fp32, row pad +1 dword
  __shared__ float s_c[16][HL_];
  __shared__ float s_h[16][HL_];
  __shared__ int   s_len[16];

  const int tid  = threadIdx.x;
  const int s0   = blockIdx.x * 16;
  const int w    = tid >> 6;
  const int lane = tid & 63;
  const int l15  = lane & 15;
  const int quad = lane >> 4;
  const int colbase = w*64;

  // B fragments: wf[nt][kt][j] = W[kt*32 + quad*8 + j][colbase + nt*16 + l15]
  bf16x8 wf[4][6];
  #pragma unroll
  for (int nt = 0; nt < 4; ++nt){
    const int col = colbase + nt*16 + l15;
    #pragma unroll
    for (int kt = 0; kt < 6; ++kt){
      #pragma unroll
      for (int j = 0; j < 8; ++j){
        int k = kt*32 + quad*8 + j;
        float v = (k < D_) ? L_Wi[k*G4_ + col] : L_Wh[(k-D_)*G4_ + col];
        wf[nt][kt][j] = f2bf(v);
      }
    }
  }
  float biasv[4];
  #pragma unroll
  for (int nt = 0; nt < 4; ++nt) biasv[nt] = L_b[colbase + nt*16 + l15];

  for (int p = tid; p < 16*HL_; p += 512){ (&s_c[0][0])[p] = 0.f; (&s_h[0][0])[p] = 0.f; }
  for (int p = tid; p < 16*AROW; p += 512) s_A[p] = 0;
  if (tid < 16) s_len[tid] = qid_len[s0 + tid];
  __syncthreads();

  // stage x(0): 16 students x 32 short2
  const int xs = tid >> 5, xpos = tid & 31;
  {
    const short2 xv = *(const short2*)&bvec[((size_t)(s0+xs)*T_ + 0)*D_ + xpos*2];
    s_A[xs*AROW + xpos*2]     = xv.x;
    s_A[xs*AROW + xpos*2 + 1] = xv.y;
  }
  int maxlen = 0;
  #pragma unroll
  for (int i = 0; i < 16; ++i) maxlen = max(maxlen, s_len[i]);
  __syncthreads();

  for (int t = 0; t < maxlen; ++t){
    // gates = bias + A @ W
    f32x4 acc[4];
    #pragma unroll
    for (int nt = 0; nt < 4; ++nt){
      f32x4 a; a[0]=biasv[nt]; a[1]=biasv[nt]; a[2]=biasv[nt]; a[3]=biasv[nt];
      acc[nt] = a;
    }
    #pragma unroll
    for (int kt = 0; kt < 6; ++kt){
      bf16x8 af = *(const bf16x8*)&s_A[l15*AROW + kt*32 + quad*8];
      #pragma unroll
      for (int nt = 0; nt < 4; ++nt)
        acc[nt] = __builtin_amdgcn_mfma_f32_16x16x32_bf16(af, wf[nt][kt], acc[nt], 0, 0, 0);
    }
    // prefetch x(t+1) while MFMAs drain (finished students read harmless junk)
    short2 xv;
    const bool havex = (t + 1 < maxlen);
    if (havex) xv = *(const short2*)&bvec[((size_t)(s0+xs)*T_ + (t+1))*D_ + xpos*2];
    // C layout: row = quad*4 + r (student), col = colbase + nt*16 + l15 (gate)
    #pragma unroll
    for (int nt = 0; nt < 4; ++nt){
      const int col = colbase + nt*16 + l15;
      #pragma unroll
      for (int r = 0; r < 4; ++r)
        s_g[(quad*4 + r)*513 + col] = acc[nt][r];
    }
    __syncthreads();
    // elementwise c/h update, masked by length
    #pragma unroll
    for (int r2 = 0; r2 < 4; ++r2){
      int p = tid + 512*r2;
      int s = p >> 7, u = p & 127;
      if (t < s_len[s]){
        float gi = s_g[s*513 + u],         gf = s_g[s*513 + HL_ + u];
        float gg = s_g[s*513 + 2*HL_ + u], go = s_g[s*513 + 3*HL_ + u];
        float c  = s_c[s][u];
        float c2 = sigmoidf_(gf)*c + sigmoidf_(gi)*tanhf(gg);
        float h2 = sigmoidf_(go)*tanhf(c2);
        s_c[s][u] = c2; s_h[s][u] = h2;
        s_A[s*AROW + D_ + u] = f2bf(h2);
      }
    }
    if (havex){
      s_A[xs*AROW + xpos*2]     = xv.x;
      s_A[xs*AROW + xpos*2 + 1] = xv.y;
    }
    __syncthreads();
  }

  // epilogue: b = 8*(sigmoid(hT@L_Wo + L_bo)-0.5); out = sigmoid(a*(t-b))
  for (int s2 = w; s2 < 16; s2 += 8){
    float part = s_h[s2][lane]*L_Wo[lane] + s_h[s2][lane+64]*L_Wo[64+lane];
    part = wave_reduce_sum(part);
    if (lane == 0){
      float bb = 8.f * (sigmoidf_(part + L_bo[0]) - 0.5f);
      out[s0+s2] = sigmoidf_(a_val[s0+s2] * (t_val[s0+s2] - bb));
    }
  }
}

// ---------------------------------------------------------------------------
extern "C" void kernel_launch(void* const* d_in, const int* in_sizes, int n_in,
                              void* d_out, int out_size, void* d_ws, size_t ws_size,
                              hipStream_t stream)
{
  (void)in_sizes; (void)n_in; (void)out_size; (void)ws_size;
  const int*   uididx    = (const int*)  d_in[0];
  const int*   kcodeidx  = (const int*)  d_in[1];
  const int*   kcode_len = (const int*)  d_in[2];
  const float* qidemb    = (const float*)d_in[3];
  const int*   qid_len   = (const int*)  d_in[4];
  const float* stuE      = (const float*)d_in[5];
  const float* knE       = (const float*)d_in[6];
  const float* T_W1      = (const float*)d_in[7];
  const float* T_b1      = (const float*)d_in[8];
  const float* T_W2      = (const float*)d_in[9];
  const float* T_b2      = (const float*)d_in[10];
  const float* A_W1      = (const float*)d_in[11];
  const float* A_b1      = (const float*)d_in[12];
  const float* A_W2      = (const float*)d_in[13];
  const float* A_b2      = (const float*)d_in[14];
  const float* L_Wi      = (const float*)d_in[15];
  const float* L_Wh      = (const float*)d_in[16];
  const float* L_b       = (const float*)d_in[17];
  const float* L_Wo      = (const float*)d_in[18];
  const float* L_bo      = (const float*)d_in[19];
  float* out = (float*)d_out;

  short* bvec  = (short*)d_ws;                       // B*T*D bf16 = 26.2 MB
  float* t_val = (float*)(bvec + (size_t)B_*T_*D_);  // B floats
  float* a_val = t_val + B_;                         // B floats

  hipLaunchKernelGGL(head_kernel, dim3(B_), dim3(256), 0, stream,
    uididx, kcodeidx, kcode_len, qidemb, qid_len, stuE, knE,
    T_W1, T_b1, T_W2, T_b2, A_W1, A_b1, A_W2, A_b2,
    bvec, t_val, a_val);

  hipLaunchKernelGGL(lstm_kernel, dim3(B_/16), dim3(512), 0, stream,
    bvec, qid_len, L_Wi, L_Wh, L_b, L_Wo, L_bo, t_val, a_val, out);
}

// Round 5
// 245.582 us; speedup vs baseline: 40.9616x; 1.2242x over previous
//
#include <hip/hip_runtime.h>
#include <math.h>

#define B_  4096
#define T_  50
#define K_  32
#define D_  64
#define H_  256
#define HL_ 128
#define G4_ 512   // 4*HL

typedef __attribute__((ext_vector_type(8))) short bf16x8;
typedef __attribute__((ext_vector_type(4))) float f32x4;

__device__ __forceinline__ float fast_exp(float x){ return __expf(x); }          // v_exp_f32 path
__device__ __forceinline__ float fast_rcp(float x){ return __builtin_amdgcn_rcpf(x); }
__device__ __forceinline__ float sigmoidf_(float x){ return fast_rcp(1.f + fast_exp(-x)); }
__device__ __forceinline__ float tanhf_(float x){ return 1.f - 2.f*fast_rcp(1.f + fast_exp(2.f*x)); }

__device__ __forceinline__ short f2bf(float f){
  union { float f; unsigned u; } v; v.f = f;
  unsigned r = v.u + 0x7FFFu + ((v.u >> 16) & 1u);   // round-to-nearest-even
  return (short)(r >> 16);
}
__device__ __forceinline__ float bf2f(short s){
  union { unsigned u; float f; } v; v.u = ((unsigned)(unsigned short)s) << 16;
  return v.f;
}

__device__ __forceinline__ float wave_reduce_sum(float v){
  #pragma unroll
  for (int off = 32; off; off >>= 1) v += __shfl_xor(v, off);
  return v;
}

// ---------------------------------------------------------------------------
// Kernel 1: per-student head (structure unchanged from R4, fast activations).
// ---------------------------------------------------------------------------
#define KROW 72
#define QROW 72
#define PROW 40

__global__ __launch_bounds__(256) void head_kernel(
    const int* __restrict__ uididx, const int* __restrict__ kcodeidx,
    const int* __restrict__ kcode_len, const float* __restrict__ qidemb,
    const int* __restrict__ qid_len, const float* __restrict__ stuE,
    const float* __restrict__ knE,
    const float* __restrict__ T_W1, const float* __restrict__ T_b1,
    const float* __restrict__ T_W2, const float* __restrict__ T_b2,
    const float* __restrict__ A_W1, const float* __restrict__ A_b1,
    const float* __restrict__ A_W2, const float* __restrict__ A_b2,
    short* __restrict__ bvec, float* __restrict__ t_val, float* __restrict__ a_val)
{
  __shared__ __align__(16) short s_kemb[K_*KROW];
  __shared__ __align__(16) short s_kembT[D_*PROW];
  __shared__ __align__(16) short s_q[64*QROW];
  __shared__ __align__(16) short s_p[64*PROW];
  __shared__ float s_stu[D_];
  __shared__ float s_mast[K_];
  __shared__ float s_kmf[K_];
  __shared__ float s_mvec[D_];
  __shared__ float s_avec[D_];
  __shared__ float s_red[4];

  const int b    = blockIdx.x;
  const int tid  = threadIdx.x;
  const int lane = tid & 63;
  const int w    = tid >> 6;
  const int l15  = lane & 15;
  const int quad = lane >> 4;
  const int klen = kcode_len[b];
  const int qlen = qid_len[b];

  if (tid < D_) s_stu[tid] = stuE[uididx[b]*D_ + tid];
  for (int idx = tid; idx < K_*D_; idx += 256){
    int k = idx >> 6, d = idx & 63;
    short bv = f2bf(knE[kcodeidx[b*K_ + k]*D_ + d]);
    s_kemb[k*KROW + d]  = bv;
    s_kembT[d*PROW + k] = bv;
  }
  for (int idx = tid; idx < 64*D_; idx += 256){
    int t = idx >> 6, d = idx & 63;
    s_q[t*QROW + d] = (t < qlen) ? f2bf(qidemb[(b*T_ + t)*D_ + d]) : (short)0;
  }
  __syncthreads();

  {
    int k = tid >> 3, l8 = tid & 7;
    float s = 0.f;
    #pragma unroll
    for (int j = 0; j < 8; ++j){
      int d = l8 + 8*((j + k) & 7);
      s += s_stu[d] * bf2f(s_kemb[k*KROW + d]);
    }
    s += __shfl_xor(s, 1); s += __shfl_xor(s, 2); s += __shfl_xor(s, 4);
    if (l8 == 0){
      float valid = (k < klen) ? 1.f : 0.f;
      s_mast[k] = valid * sigmoidf_(s * 0.2f);
      s_kmf[k]  = valid;
    }
  }
  __syncthreads();

  if (tid < D_){
    float mv = 0.f, av = 0.f;
    #pragma unroll 4
    for (int k = 0; k < K_; ++k){
      float e = bf2f(s_kemb[k*KROW + tid]);
      mv += s_mast[k] * e;
      av += s_kmf[k]  * e;
    }
    s_mvec[tid] = mv; s_avec[tid] = av;
  }
  __syncthreads();

  // ---- attention via MFMA ----
  {
    f32x4 zero = {0.f, 0.f, 0.f, 0.f};
    f32x4 accs[2] = {zero, zero};
    #pragma unroll
    for (int kt = 0; kt < 2; ++kt){
      bf16x8 aq = *(const bf16x8*)&s_q[(w*16 + l15)*QROW + kt*32 + quad*8];
      #pragma unroll
      for (int nt = 0; nt < 2; ++nt){
        bf16x8 bk = *(const bf16x8*)&s_kemb[(nt*16 + l15)*KROW + kt*32 + quad*8];
        accs[nt] = __builtin_amdgcn_mfma_f32_16x16x32_bf16(aq, bk, accs[nt], 0, 0, 0);
      }
    }
    #pragma unroll
    for (int r = 0; r < 4; ++r){
      float v0 = (l15      < klen) ? accs[0][r]*0.15f : -1e9f;
      float v1 = (l15 + 16 < klen) ? accs[1][r]*0.15f : -1e9f;
      float mx = fmaxf(v0, v1);
      #pragma unroll
      for (int off = 1; off < 16; off <<= 1) mx = fmaxf(mx, __shfl_xor(mx, off));
      float e0 = fast_exp(v0 - mx), e1 = fast_exp(v1 - mx);
      float sm = e0 + e1;
      #pragma unroll
      for (int off = 1; off < 16; off <<= 1) sm += __shfl_xor(sm, off);
      float inv = fast_rcp(sm);
      int row = w*16 + quad*4 + r;
      s_p[row*PROW + l15]      = f2bf(e0 * inv);
      s_p[row*PROW + 16 + l15] = f2bf(e1 * inv);
    }
    bf16x8 ap = *(const bf16x8*)&s_p[(w*16 + l15)*PROW + quad*8];
    #pragma unroll
    for (int nt = 0; nt < 4; ++nt){
      bf16x8 bv = *(const bf16x8*)&s_kembT[(nt*16 + l15)*PROW + quad*8];
      f32x4 acco = __builtin_amdgcn_mfma_f32_16x16x32_bf16(ap, bv, zero, 0, 0, 0);
      #pragma unroll
      for (int r = 0; r < 4; ++r){
        int t = w*16 + quad*4 + r;
        if (t < qlen) bvec[((size_t)b*T_ + t)*D_ + nt*16 + l15] = f2bf(acco[r]);
      }
    }
  }

  // theta DNN
  {
    float acc = T_b1[tid];
    for (int d = 0; d < D_; ++d) acc += s_mvec[d] * T_W1[d*H_ + tid];
    float term = tanhf_(acc) * T_W2[tid];
    term = wave_reduce_sum(term);
    if (lane == 0) s_red[w] = term;
    __syncthreads();
    if (tid == 0) t_val[b] = s_red[0] + s_red[1] + s_red[2] + s_red[3] + T_b2[0];
    __syncthreads();
  }
  // a DNN
  {
    float acc = A_b1[tid];
    for (int d = 0; d < D_; ++d) acc += s_avec[d] * A_W1[d*H_ + tid];
    float term = tanhf_(acc) * A_W2[tid];
    term = wave_reduce_sum(term);
    if (lane == 0) s_red[w] = term;
    __syncthreads();
    if (tid == 0){
      float v = s_red[0] + s_red[1] + s_red[2] + s_red[3] + A_b2[0];
      a_val[b] = 8.f * (sigmoidf_(fabsf(v)) - 0.5f);
    }
  }
}

// ---------------------------------------------------------------------------
// Kernel 2: MFMA LSTM, gate-major column permutation.
// Wave w owns cols {g*128 + w*16 + l15 : g=0..3} -> after the 24 MFMAs each
// thread holds ALL FOUR gates for its 4 (student,unit) pairs in registers.
// c,h live in VGPRs; h double-buffered in LDS (bf16) for the A-operand; x
// double-buffered. ONE barrier per step; s_g round-trip deleted (R4: 5.4e6
// bank conflicts, 2 barriers). Fast sigmoid/tanh via v_exp_f32.
// ---------------------------------------------------------------------------
#define AROW 392   // shorts/row: x0(64)|x1(64)|h0(128)|h1(128)|pad(8); 784B, 16B-aligned

__global__ __launch_bounds__(512, 2) void lstm_kernel(
    const short* __restrict__ bvec, const int* __restrict__ qid_len,
    const float* __restrict__ L_Wi, const float* __restrict__ L_Wh,
    const float* __restrict__ L_b,  const float* __restrict__ L_Wo,
    const float* __restrict__ L_bo, const float* __restrict__ t_val,
    const float* __restrict__ a_val, float* __restrict__ out)
{
  __shared__ __align__(16) short s_A[16*AROW];
  __shared__ float s_h[16][HL_];     // fp32 final h for epilogue
  __shared__ int   s_len[16];

  const int tid  = threadIdx.x;
  const int s0   = blockIdx.x * 16;
  const int w    = tid >> 6;
  const int lane = tid & 63;
  const int l15  = lane & 15;
  const int quad = lane >> 4;

  // gate-major weight fragments: wf[g][kt][j] = W[kt*32+quad*8+j][g*128 + w*16 + l15]
  bf16x8 wf[4][6];
  float  biasv[4];
  #pragma unroll
  for (int g = 0; g < 4; ++g){
    const int col = g*128 + w*16 + l15;
    biasv[g] = L_b[col];
    #pragma unroll
    for (int kt = 0; kt < 6; ++kt){
      #pragma unroll
      for (int j = 0; j < 8; ++j){
        int k = kt*32 + quad*8 + j;
        float v = (k < D_) ? L_Wi[k*G4_ + col] : L_Wh[(k-D_)*G4_ + col];
        wf[g][kt][j] = f2bf(v);
      }
    }
  }

  for (int p = tid; p < 16*AROW; p += 512) s_A[p] = 0;
  for (int p = tid; p < 16*HL_; p += 512) (&s_h[0][0])[p] = 0.f;
  if (tid < 16) s_len[tid] = qid_len[s0 + tid];
  __syncthreads();

  // stage x(0) into x-buf 0
  const int xs = tid >> 5, xpos = tid & 31;
  {
    const short2 xv = *(const short2*)&bvec[((size_t)(s0+xs)*T_ + 0)*D_ + xpos*2];
    *(short2*)&s_A[xs*AROW + xpos*2] = xv;
  }
  int maxlen = 0;
  int len_r[4];
  #pragma unroll
  for (int i = 0; i < 16; ++i) maxlen = max(maxlen, s_len[i]);
  #pragma unroll
  for (int r = 0; r < 4; ++r) len_r[r] = s_len[quad*4 + r];
  float c_reg[4] = {0.f,0.f,0.f,0.f};
  float h_reg[4] = {0.f,0.f,0.f,0.f};
  __syncthreads();

  for (int t = 0; t < maxlen; ++t){
    const int xb = t & 1;          // x(t) buffer; h(t-1) lives in buffer xb^1
    const int hb = xb ^ 1;
    // issue x(t+1) global load early
    short2 xv;
    const bool havex = (t + 1 < maxlen);
    if (havex) xv = *(const short2*)&bvec[((size_t)(s0+xs)*T_ + (t+1))*D_ + xpos*2];

    // A fragments
    bf16x8 af[6];
    af[0] = *(const bf16x8*)&s_A[l15*AROW + xb*64 +      quad*8];
    af[1] = *(const bf16x8*)&s_A[l15*AROW + xb*64 + 32 + quad*8];
    #pragma unroll
    for (int kt = 0; kt < 4; ++kt)
      af[2+kt] = *(const bf16x8*)&s_A[l15*AROW + 128 + hb*128 + kt*32 + quad*8];

    f32x4 acc[4];
    #pragma unroll
    for (int g = 0; g < 4; ++g){
      f32x4 a; a[0]=biasv[g]; a[1]=biasv[g]; a[2]=biasv[g]; a[3]=biasv[g];
      acc[g] = a;
    }
    #pragma unroll
    for (int kt = 0; kt < 6; ++kt){
      #pragma unroll
      for (int g = 0; g < 4; ++g)
        acc[g] = __builtin_amdgcn_mfma_f32_16x16x32_bf16(af[kt], wf[g][kt], acc[g], 0, 0, 0);
    }

    // store x(t+1) into buffer xb^1 (disjoint from this step's readers)
    if (havex) *(short2*)&s_A[xs*AROW + hb*64 + xpos*2] = xv;

    // elementwise straight out of the accumulators
    #pragma unroll
    for (int r = 0; r < 4; ++r){
      if (t < len_r[r]){
        float gi = acc[0][r], gf = acc[1][r], gg = acc[2][r], go = acc[3][r];
        float c2 = sigmoidf_(gf)*c_reg[r] + sigmoidf_(gi)*tanhf_(gg);
        float h2 = sigmoidf_(go)*tanhf_(c2);
        c_reg[r] = c2; h_reg[r] = h2;
        s_h[quad*4 + r][w*16 + l15] = h2;
      }
      // always refresh current h buffer (keeps frozen students coherent)
      s_A[(quad*4 + r)*AROW + 128 + xb*128 + w*16 + l15] = f2bf(h_reg[r]);
    }
    __syncthreads();
  }

  // epilogue: b = 8*(sigmoid(hT@L_Wo + L_bo)-0.5); out = sigmoid(a*(t-b))
  for (int s2 = w; s2 < 16; s2 += 8){
    float part = s_h[s2][lane]*L_Wo[lane] + s_h[s2][lane+64]*L_Wo[64+lane];
    part = wave_reduce_sum(part);
    if (lane == 0){
      float bb = 8.f * (sigmoidf_(part + L_bo[0]) - 0.5f);
      out[s0+s2] = sigmoidf_(a_val[s0+s2] * (t_val[s0+s2] - bb));
    }
  }
}

// ---------------------------------------------------------------------------
extern "C" void kernel_launch(void* const* d_in, const int* in_sizes, int n_in,
                              void* d_out, int out_size, void* d_ws, size_t ws_size,
                              hipStream_t stream)
{
  (void)in_sizes; (void)n_in; (void)out_size; (void)ws_size;
  const int*   uididx    = (const int*)  d_in[0];
  const int*   kcodeidx  = (const int*)  d_in[1];
  const int*   kcode_len = (const int*)  d_in[2];
  const float* qidemb    = (const float*)d_in[3];
  const int*   qid_len   = (const int*)  d_in[4];
  const float* stuE      = (const float*)d_in[5];
  const float* knE       = (const float*)d_in[6];
  const float* T_W1      = (const float*)d_in[7];
  const float* T_b1      = (const float*)d_in[8];
  const float* T_W2      = (const float*)d_in[9];
  const float* T_b2      = (const float*)d_in[10];
  const float* A_W1      = (const float*)d_in[11];
  const float* A_b1      = (const float*)d_in[12];
  const float* A_W2      = (const float*)d_in[13];
  const float* A_b2      = (const float*)d_in[14];
  const float* L_Wi      = (const float*)d_in[15];
  const float* L_Wh      = (const float*)d_in[16];
  const float* L_b       = (const float*)d_in[17];
  const float* L_Wo      = (const float*)d_in[18];
  const float* L_bo      = (const float*)d_in[19];
  float* out = (float*)d_out;

  short* bvec  = (short*)d_ws;                       // B*T*D bf16 = 26.2 MB
  float* t_val = (float*)(bvec + (size_t)B_*T_*D_);  // B floats
  float* a_val = t_val + B_;                         // B floats

  hipLaunchKernelGGL(head_kernel, dim3(B_), dim3(256), 0, stream,
    uididx, kcodeidx, kcode_len, qidemb, qid_len, stuE, knE,
    T_W1, T_b1, T_W2, T_b2, A_W1, A_b1, A_W2, A_b2,
    bvec, t_val, a_val);

  hipLaunchKernelGGL(lstm_kernel, dim3(B_/16), dim3(512), 0, stream,
    bvec, qid_len, L_Wi, L_Wh, L_b, L_Wo, L_bo, t_val, a_val, out);
}